// Round 1
// baseline (248.700 us; speedup 1.0000x reference)
//
#include <hip/hip_runtime.h>
#include <math.h>

#define EPS 1e-8f
constexpr int D    = 1024;
constexpr int NEMB = 80;
constexpr int K    = 1849;
constexpr int BATCH = 4;
constexpr int P    = 43;
constexpr int TGT  = 602;
constexpr int ROWS = BATCH * K; // 7396

// ---------------- bicubic tap table (exact fp64, matches numpy) -------------
__device__ inline double cubic_w(double x) {
  const double A = -0.75;
  x = fabs(x);
  if (x <= 1.0) return ((A + 2.0) * x - (A + 3.0)) * x * x + 1.0;
  if (x < 2.0)  return A * (((x - 5.0) * x + 8.0) * x - 4.0);
  return 0.0;
}

__global__ void build_table(int* __restrict__ tb, float4* __restrict__ tw) {
  int i = blockIdx.x * blockDim.x + threadIdx.x;
  if (i >= TGT) return;
  double scale = (double)P / (double)TGT;   // exactly 1/14
  double src = ((double)i + 0.5) * scale - 0.5;
  double fb = floor(src);
  double t = src - fb;
  float4 w;
  w.x = (float)cubic_w(t + 1.0);  // tap -1
  w.y = (float)cubic_w(t);        // tap  0
  w.z = (float)cubic_w(t - 1.0);  // tap +1
  w.w = (float)cubic_w(t - 2.0);  // tap +2
  tb[i] = (int)fb - 1;            // index of tap -1 (clamped by consumer)
  tw[i] = w;
}

// ---------------- norms ------------------------------------------------------
__device__ inline float block_reduce_sum256(float v) {
  #pragma unroll
  for (int off = 32; off > 0; off >>= 1) v += __shfl_down(v, off, 64);
  __shared__ float red[4];
  int lane = threadIdx.x & 63, wid = threadIdx.x >> 6;
  if (lane == 0) red[wid] = v;
  __syncthreads();
  float r = 0.f;
  if (threadIdx.x == 0) r = red[0] + red[1] + red[2] + red[3];
  return r;
}

// one block per row; rows [0,ROWS) = feats, [ROWS, ROWS+NEMB) = embeddings
__global__ __launch_bounds__(256) void norms_kernel(
    const float* __restrict__ feats, const float* __restrict__ emb,
    float* __restrict__ f_norm, float* __restrict__ e_norm) {
  int row = blockIdx.x;
  const float* src;
  float* dst;
  if (row < ROWS) { src = feats + (size_t)row * D; dst = f_norm + row; }
  else            { src = emb + (size_t)(row - ROWS) * D; dst = e_norm + (row - ROWS); }
  float4 v = ((const float4*)src)[threadIdx.x]; // 256*4 == 1024 exactly
  float s = v.x * v.x + v.y * v.y + v.z * v.z + v.w * v.w;
  s = block_reduce_sum256(s);
  if (threadIdx.x == 0) *dst = sqrtf(s);
}

// ---------------- cosine-sim GEMM: [7396 x 1024] x [1024 x 80] ---------------
constexpr int BM  = 64;
constexpr int BK  = 32;
constexpr int LDA = 36; // padded row stride (floats), 16B aligned

__global__ __launch_bounds__(256) void gemm_cosim(
    const float* __restrict__ feats, const float* __restrict__ emb,
    const float* __restrict__ f_norm, const float* __restrict__ e_norm,
    float* __restrict__ cosim) {
  __shared__ float As[BM * LDA];    // 9216 B
  __shared__ float Bs[NEMB * LDA];  // 11520 B
  int t = threadIdx.x;
  int row0 = blockIdx.x * BM;
  int tr = t >> 4, tc = t & 15;     // 16x16 thread grid
  float acc[4][5] = {{0.f}};

  for (int k0 = 0; k0 < D; k0 += BK) {
    // stage A tile: 64 rows x 32 d  (512 float4, 2/thread)
    #pragma unroll
    for (int it = 0; it < 2; ++it) {
      int i = t + it * 256;
      int r = i >> 3, dg = i & 7;
      int gr = row0 + r;
      float4 v = make_float4(0.f, 0.f, 0.f, 0.f);
      if (gr < ROWS) v = *(const float4*)(feats + (size_t)gr * D + k0 + dg * 4);
      *(float4*)(As + r * LDA + dg * 4) = v;
    }
    // stage B tile: 80 rows x 32 d (640 float4)
    #pragma unroll
    for (int it = 0; it < 3; ++it) {
      int i = t + it * 256;
      if (i < NEMB * 8) {
        int r = i >> 3, dg = i & 7;
        float4 v = *(const float4*)(emb + (size_t)r * D + k0 + dg * 4);
        *(float4*)(Bs + r * LDA + dg * 4) = v;
      }
    }
    __syncthreads();
    #pragma unroll
    for (int dd = 0; dd < BK; dd += 4) {
      float4 a[4], b[5];
      #pragma unroll
      for (int j = 0; j < 4; ++j)  a[j]  = *(const float4*)(As + (tr * 4 + j) * LDA + dd);
      #pragma unroll
      for (int i2 = 0; i2 < 5; ++i2) b[i2] = *(const float4*)(Bs + (tc + i2 * 16) * LDA + dd);
      #pragma unroll
      for (int j = 0; j < 4; ++j)
        #pragma unroll
        for (int i2 = 0; i2 < 5; ++i2)
          acc[j][i2] += a[j].x * b[i2].x + a[j].y * b[i2].y +
                        a[j].z * b[i2].z + a[j].w * b[i2].w;
    }
    __syncthreads();
  }

  // epilogue: divide by norms, write cosim[b][n][k]
  #pragma unroll
  for (int j = 0; j < 4; ++j) {
    int gr = row0 + tr * 4 + j;
    if (gr >= ROWS) continue;
    int b_ = gr / K;
    int k  = gr - b_ * K;
    float fn = f_norm[gr];
    #pragma unroll
    for (int i2 = 0; i2 < 5; ++i2) {
      int n = tc + i2 * 16;
      float denom = fn * e_norm[n] + EPS;
      cosim[((size_t)(b_ * NEMB + n)) * K + k] = acc[j][i2] / denom;
    }
  }
}

// ---------------- separable bicubic resize -----------------------------------
// grid: x = 43 chunks of 14 output rows, y = 320 images (b*80+n)
__global__ __launch_bounds__(256) void resize_kernel(
    const float* __restrict__ cosim, const int* __restrict__ tb,
    const float4* __restrict__ tw, float* __restrict__ out) {
  __shared__ float img[P * P];     // 1849 floats
  __shared__ float tmp[5 * TGT];   // up to 5 input rows, W-resized

  int bn = blockIdx.y;
  int c  = blockIdx.x;             // output row chunk; H0 = 14*c
  int t  = threadIdx.x;

  const float* src = cosim + (size_t)bn * (P * P);
  for (int i = t; i < P * P; i += 256) img[i] = src[i];

  int hmin = max(0, c - 2), hmax = min(P - 1, c + 2);
  int NH = hmax - hmin + 1;
  __syncthreads();

  // phase 1: horizontal (W) resize for the NH needed input rows
  for (int i = t; i < NH * TGT; i += 256) {
    int hrel = i / TGT;
    int W = i - hrel * TGT;
    int h = hmin + hrel;
    int wb = tb[W];
    float4 w = tw[W];
    const float* rowp = img + h * P;
    int i0 = max(0, min(P - 1, wb));
    int i1 = max(0, min(P - 1, wb + 1));
    int i2 = max(0, min(P - 1, wb + 2));
    int i3 = max(0, min(P - 1, wb + 3));
    tmp[hrel * TGT + W] = w.x * rowp[i0] + w.y * rowp[i1] +
                          w.z * rowp[i2] + w.w * rowp[i3];
  }
  __syncthreads();

  // phase 2: vertical (H) resize, 14 output rows
  int H0 = c * 14;
  float* obase = out + (size_t)bn * TGT * TGT;
  for (int r = 0; r < 14; ++r) {
    int H = H0 + r;
    int hb = tb[H];
    float4 hw = tw[H];
    int r0 = max(0, min(P - 1, hb))     - hmin;
    int r1 = max(0, min(P - 1, hb + 1)) - hmin;
    int r2 = max(0, min(P - 1, hb + 2)) - hmin;
    int r3 = max(0, min(P - 1, hb + 3)) - hmin;
    float* orow = obase + (size_t)H * TGT;
    for (int W = t; W < TGT; W += 256) {
      orow[W] = hw.x * tmp[r0 * TGT + W] + hw.y * tmp[r1 * TGT + W] +
                hw.z * tmp[r2 * TGT + W] + hw.w * tmp[r3 * TGT + W];
    }
  }
}

// ---------------- launch ------------------------------------------------------
extern "C" void kernel_launch(void* const* d_in, const int* in_sizes, int n_in,
                              void* d_out, int out_size, void* d_ws, size_t ws_size,
                              hipStream_t stream) {
  const float* feats = (const float*)d_in[0];
  const float* emb   = (const float*)d_in[1];
  float* out = (float*)d_out;
  char* ws = (char*)d_ws;

  // workspace layout (all 16B aligned)
  constexpr size_t COSIM_BYTES = (size_t)BATCH * NEMB * K * 4; // 2,366,720
  float* cosim  = (float*)(ws);
  float* f_norm = (float*)(ws + COSIM_BYTES);                   // 29,584 B
  float* e_norm = (float*)(ws + COSIM_BYTES + 29584);           // 320 B
  int*   tb     = (int*)  (ws + COSIM_BYTES + 29584 + 320);     // 2,408 B
  float4* tw    = (float4*)(ws + COSIM_BYTES + 29584 + 320 + 2416);

  build_table<<<dim3((TGT + 255) / 256), dim3(256), 0, stream>>>(tb, tw);
  norms_kernel<<<dim3(ROWS + NEMB), dim3(256), 0, stream>>>(feats, emb, f_norm, e_norm);
  gemm_cosim<<<dim3((ROWS + BM - 1) / BM), dim3(256), 0, stream>>>(feats, emb, f_norm, e_norm, cosim);
  resize_kernel<<<dim3(43, 320), dim3(256), 0, stream>>>(cosim, tb, tw, out);
}

// Round 2
// 193.143 us; speedup vs baseline: 1.2876x; 1.2876x over previous
//
#include <hip/hip_runtime.h>
#include <math.h>

#define EPS 1e-8f
constexpr int D     = 1024;
constexpr int NEMB  = 80;
constexpr int K     = 1849;
constexpr int BATCH = 4;
constexpr int P     = 43;
constexpr int TGT   = 602;
constexpr int ROWS  = BATCH * K;                  // 7396
constexpr size_t PLANE = (size_t)BATCH * NEMB * K; // 591,680 elements

// ---------------- bicubic tap weights (exact fp64, matches numpy) -----------
__device__ inline double cubic_w(double x) {
  const double A = -0.75;
  x = fabs(x);
  if (x <= 1.0) return ((A + 2.0) * x - (A + 3.0)) * x * x + 1.0;
  if (x < 2.0)  return A * (((x - 5.0) * x + 8.0) * x - 4.0);
  return 0.0;
}

__device__ inline float block_reduce_sum256(float v) {
  #pragma unroll
  for (int off = 32; off > 0; off >>= 1) v += __shfl_down(v, off, 64);
  __shared__ float red[4];
  int lane = threadIdx.x & 63, wid = threadIdx.x >> 6;
  if (lane == 0) red[wid] = v;
  __syncthreads();
  float r = 0.f;
  if (threadIdx.x == 0) r = red[0] + red[1] + red[2] + red[3];
  return r;
}

// blocks 0..79: e_norm rows; blocks 80..82: tap table (602 entries)
__global__ __launch_bounds__(256) void prep_kernel(
    const float* __restrict__ emb, float* __restrict__ e_norm,
    int* __restrict__ tb, float4* __restrict__ tw) {
  int bid = blockIdx.x;
  if (bid < NEMB) {
    float4 v = ((const float4*)(emb + (size_t)bid * D))[threadIdx.x];
    float s = v.x * v.x + v.y * v.y + v.z * v.z + v.w * v.w;
    s = block_reduce_sum256(s);
    if (threadIdx.x == 0) e_norm[bid] = sqrtf(s);
  } else {
    int i = (bid - NEMB) * 256 + threadIdx.x;
    if (i < TGT) {
      double scale = (double)P / (double)TGT;
      double src = ((double)i + 0.5) * scale - 0.5;
      double fb = floor(src);
      double t = src - fb;
      float4 w;
      w.x = (float)cubic_w(t + 1.0);
      w.y = (float)cubic_w(t);
      w.z = (float)cubic_w(t - 1.0);
      w.w = (float)cubic_w(t - 2.0);
      tb[i] = (int)fb - 1;
      tw[i] = w;
    }
  }
}

// -------- split-K GEMM: partial dot [s][b][n][k] + partial sumsq [s][gr] ----
constexpr int BM  = 64;
constexpr int BK  = 32;
constexpr int LDA = 36; // padded LDS row stride (floats), 16B aligned

__global__ __launch_bounds__(256) void gemm_partial(
    const float* __restrict__ feats, const float* __restrict__ emb,
    float* __restrict__ part, float* __restrict__ fpart, int kc) {
  __shared__ float As[BM * LDA];
  __shared__ float Bs[NEMB * LDA];
  int t = threadIdx.x;
  int row0 = blockIdx.x * BM;
  int s = blockIdx.y;
  int tr = t >> 4, tc = t & 15;
  float acc[4][5] = {{0.f}};
  float ssq0 = 0.f, ssq1 = 0.f;

  int kbeg = s * kc, kend = kbeg + kc;
  for (int k0 = kbeg; k0 < kend; k0 += BK) {
    // stage A: rows 0..31 (it=0) and 32..63 (it=1), 8 threads/row
    int r = t >> 3, dg = t & 7;
    {
      int gr = row0 + r;
      float4 v = make_float4(0.f, 0.f, 0.f, 0.f);
      if (gr < ROWS) v = *(const float4*)(feats + (size_t)gr * D + k0 + dg * 4);
      ssq0 += v.x * v.x + v.y * v.y + v.z * v.z + v.w * v.w;
      *(float4*)(As + r * LDA + dg * 4) = v;
    }
    {
      int gr = row0 + 32 + r;
      float4 v = make_float4(0.f, 0.f, 0.f, 0.f);
      if (gr < ROWS) v = *(const float4*)(feats + (size_t)gr * D + k0 + dg * 4);
      ssq1 += v.x * v.x + v.y * v.y + v.z * v.z + v.w * v.w;
      *(float4*)(As + (32 + r) * LDA + dg * 4) = v;
    }
    // stage B: 80 rows x 32 d (640 float4)
    #pragma unroll
    for (int it = 0; it < 3; ++it) {
      int i = t + it * 256;
      if (i < NEMB * 8) {
        int rb = i >> 3, dgb = i & 7;
        float4 v = *(const float4*)(emb + (size_t)rb * D + k0 + dgb * 4);
        *(float4*)(Bs + rb * LDA + dgb * 4) = v;
      }
    }
    __syncthreads();
    #pragma unroll
    for (int dd = 0; dd < BK; dd += 4) {
      float4 a[4], b[5];
      #pragma unroll
      for (int j = 0; j < 4; ++j)  a[j]  = *(const float4*)(As + (tr * 4 + j) * LDA + dd);
      #pragma unroll
      for (int i2 = 0; i2 < 5; ++i2) b[i2] = *(const float4*)(Bs + (tc + i2 * 16) * LDA + dd);
      #pragma unroll
      for (int j = 0; j < 4; ++j)
        #pragma unroll
        for (int i2 = 0; i2 < 5; ++i2)
          acc[j][i2] += a[j].x * b[i2].x + a[j].y * b[i2].y +
                        a[j].z * b[i2].z + a[j].w * b[i2].w;
    }
    __syncthreads();
  }

  // reduce per-row sumsq across the 8 staging lanes of each row
  #pragma unroll
  for (int off = 4; off > 0; off >>= 1) {
    ssq0 += __shfl_down(ssq0, off, 8);
    ssq1 += __shfl_down(ssq1, off, 8);
  }
  if ((t & 7) == 0) {
    int r = t >> 3;
    int gr0 = row0 + r, gr1 = row0 + 32 + r;
    if (gr0 < ROWS) fpart[(size_t)s * ROWS + gr0] = ssq0;
    if (gr1 < ROWS) fpart[(size_t)s * ROWS + gr1] = ssq1;
  }

  // write partial dot plane s (layout [b][n][k], same as cosim)
  float* pplane = part + (size_t)s * PLANE;
  #pragma unroll
  for (int j = 0; j < 4; ++j) {
    int gr = row0 + tr * 4 + j;
    if (gr >= ROWS) continue;
    int b_ = gr / K;
    int k  = gr - b_ * K;
    #pragma unroll
    for (int i2 = 0; i2 < 5; ++i2) {
      int n = tc + i2 * 16;
      pplane[((size_t)(b_ * NEMB + n)) * K + k] = acc[j][i2];
    }
  }
}

// -------- reduce partials -> cosim (all loads/stores coalesced) --------------
__global__ __launch_bounds__(256) void reduce_kernel(
    const float* __restrict__ part, const float* __restrict__ fpart,
    const float* __restrict__ e_norm, float* __restrict__ cosim, int split) {
  size_t e = (size_t)blockIdx.x * 256 + threadIdx.x;
  if (e >= PLANE) return;
  int bn = (int)(e / K);
  int k  = (int)(e - (size_t)bn * K);
  int b_ = bn / NEMB;
  int n  = bn - b_ * NEMB;
  int gr = b_ * K + k;
  float dot = 0.f, fn2 = 0.f;
  for (int s = 0; s < split; ++s) {
    dot += part[(size_t)s * PLANE + e];
    fn2 += fpart[(size_t)s * ROWS + gr];
  }
  cosim[e] = dot / (sqrtf(fn2) * e_norm[n] + EPS);
}

// ---------------- separable bicubic resize -----------------------------------
// grid: x = 43 chunks of 14 output rows, y = 320 images (b*80+n)
__global__ __launch_bounds__(256) void resize_kernel(
    const float* __restrict__ cosim, const int* __restrict__ tb,
    const float4* __restrict__ tw, float* __restrict__ out) {
  __shared__ float img[5 * P];      // only the 5 needed input rows
  __shared__ float tmp[5 * TGT];    // W-resized rows

  int bn = blockIdx.y;
  int c  = blockIdx.x;
  int t  = threadIdx.x;

  int hmin = max(0, c - 2), hmax = min(P - 1, c + 2);
  int NH = hmax - hmin + 1;

  const float* src = cosim + (size_t)bn * (P * P) + hmin * P;
  for (int i = t; i < NH * P; i += 256) img[i] = src[i];
  __syncthreads();

  // phase 1: horizontal (W) resize of the NH staged rows
  for (int i = t; i < NH * TGT; i += 256) {
    int hrel = i / TGT;
    int W = i - hrel * TGT;
    int wb = tb[W];
    float4 w = tw[W];
    const float* rowp = img + hrel * P;
    int i0 = max(0, min(P - 1, wb));
    int i1 = max(0, min(P - 1, wb + 1));
    int i2 = max(0, min(P - 1, wb + 2));
    int i3 = max(0, min(P - 1, wb + 3));
    tmp[i] = w.x * rowp[i0] + w.y * rowp[i1] +
             w.z * rowp[i2] + w.w * rowp[i3];
  }
  __syncthreads();

  // phase 2: vertical (H) resize, float2 output pairs (602 is even, rows 8B-aligned)
  int H0 = c * 14;
  float* obase = out + (size_t)bn * TGT * TGT;
  constexpr int PAIRS = TGT / 2; // 301
  for (int i = t; i < 14 * PAIRS; i += 256) {
    int r  = i / PAIRS;
    int pw = i - r * PAIRS;
    int H = H0 + r;
    int hb = tb[H];
    float4 hw = tw[H];
    int r0 = max(0, min(P - 1, hb))     - hmin;
    int r1 = max(0, min(P - 1, hb + 1)) - hmin;
    int r2 = max(0, min(P - 1, hb + 2)) - hmin;
    int r3 = max(0, min(P - 1, hb + 3)) - hmin;
    float2 a0 = *(const float2*)(tmp + r0 * TGT + pw * 2);
    float2 a1 = *(const float2*)(tmp + r1 * TGT + pw * 2);
    float2 a2 = *(const float2*)(tmp + r2 * TGT + pw * 2);
    float2 a3 = *(const float2*)(tmp + r3 * TGT + pw * 2);
    float2 o;
    o.x = hw.x * a0.x + hw.y * a1.x + hw.z * a2.x + hw.w * a3.x;
    o.y = hw.x * a0.y + hw.y * a1.y + hw.z * a2.y + hw.w * a3.y;
    *(float2*)(obase + (size_t)H * TGT + pw * 2) = o;
  }
}

// ---------------- launch ------------------------------------------------------
extern "C" void kernel_launch(void* const* d_in, const int* in_sizes, int n_in,
                              void* d_out, int out_size, void* d_ws, size_t ws_size,
                              hipStream_t stream) {
  const float* feats = (const float*)d_in[0];
  const float* emb   = (const float*)d_in[1];
  float* out = (float*)d_out;
  char* ws = (char*)d_ws;

  auto align64 = [](size_t x) { return (x + 63) & ~(size_t)63; };
  size_t off = 0;
  float* cosim  = (float*)(ws + off); off = align64(off + PLANE * 4);
  float* e_norm = (float*)(ws + off); off = align64(off + NEMB * 4);
  int*   tb     = (int*)  (ws + off); off = align64(off + TGT * 4);
  float4* tw    = (float4*)(ws + off); off = align64(off + TGT * 16);

  // pick split-K factor based on available workspace
  int split = 1;
  {
    const int cands[4] = {8, 4, 2, 1};
    for (int ci = 0; ci < 4; ++ci) {
      int c = cands[ci];
      size_t need = align64(off + (size_t)c * ROWS * 4) + (size_t)c * PLANE * 4;
      if (ws_size >= need) { split = c; break; }
    }
  }
  float* fpart = (float*)(ws + off); off = align64(off + (size_t)split * ROWS * 4);
  float* part  = (float*)(ws + off);
  int kc = D / split;

  prep_kernel<<<dim3(NEMB + 3), dim3(256), 0, stream>>>(emb, e_norm, tb, tw);
  gemm_partial<<<dim3((ROWS + BM - 1) / BM, split), dim3(256), 0, stream>>>(
      feats, emb, part, fpart, kc);
  reduce_kernel<<<dim3((int)((PLANE + 255) / 256)), dim3(256), 0, stream>>>(
      part, fpart, e_norm, cosim, split);
  resize_kernel<<<dim3(43, 320), dim3(256), 0, stream>>>(cosim, tb, tw, out);
}

// Round 3
// 187.099 us; speedup vs baseline: 1.3292x; 1.0323x over previous
//
#include <hip/hip_runtime.h>
#include <math.h>

#define EPS 1e-8f
constexpr int D     = 1024;
constexpr int NEMB  = 80;
constexpr int K     = 1849;
constexpr int BATCH = 4;
constexpr int P     = 43;
constexpr int TGT   = 602;
constexpr int ROWS  = BATCH * K;                   // 7396
constexpr size_t PLANE = (size_t)BATCH * NEMB * K; // 591,680
constexpr int SPLIT = 8;
constexpr int KC    = D / SPLIT;                   // 128

// ---------------- bicubic tap weights (exact fp64, matches numpy) -----------
__device__ inline double cubic_w(double x) {
  const double A = -0.75;
  x = fabs(x);
  if (x <= 1.0) return ((A + 2.0) * x - (A + 3.0)) * x * x + 1.0;
  if (x < 2.0)  return A * (((x - 5.0) * x + 8.0) * x - 4.0);
  return 0.0;
}

__device__ inline float block_reduce_sum256(float v) {
  #pragma unroll
  for (int off = 32; off > 0; off >>= 1) v += __shfl_down(v, off, 64);
  __shared__ float red[4];
  int lane = threadIdx.x & 63, wid = threadIdx.x >> 6;
  if (lane == 0) red[wid] = v;
  __syncthreads();
  float r = 0.f;
  if (threadIdx.x == 0) r = red[0] + red[1] + red[2] + red[3];
  return r;
}

// blocks 0..79: e_norm rows; block 80: the 14-entry periodic weight table.
// (scale = 43/602 = 1/14 exactly -> weights repeat with period 14 and
//  base(i) = i/14 - 2 + (i%14 >= 7) exactly; fp64 src is never within
//  1/28 of an integer so floor is rounding-robust.)
__global__ __launch_bounds__(256) void prep_kernel(
    const float* __restrict__ emb, float* __restrict__ e_norm,
    float4* __restrict__ gtw) {
  int bid = blockIdx.x;
  if (bid < NEMB) {
    float4 v = ((const float4*)(emb + (size_t)bid * D))[threadIdx.x];
    float s = v.x * v.x + v.y * v.y + v.z * v.z + v.w * v.w;
    s = block_reduce_sum256(s);
    if (threadIdx.x == 0) e_norm[bid] = sqrtf(s);
  } else {
    int j = threadIdx.x;
    if (j < 14) {
      double scale = (double)P / (double)TGT;
      double src = ((double)j + 0.5) * scale - 0.5;
      double fb = floor(src);
      double t = src - fb;
      float4 w;
      w.x = (float)cubic_w(t + 1.0);
      w.y = (float)cubic_w(t);
      w.z = (float)cubic_w(t - 1.0);
      w.w = (float)cubic_w(t - 2.0);
      gtw[j] = w;
    }
  }
}

// -------- split-K GEMM: partial dot [s][b][n][k] + partial sumsq [s][gr] ----
constexpr int BM  = 64;
constexpr int BK  = 32;
constexpr int LDA = 36; // padded LDS row stride (floats), 16B aligned

__global__ __launch_bounds__(256) void gemm_partial(
    const float* __restrict__ feats, const float* __restrict__ emb,
    float* __restrict__ part, float* __restrict__ fpart) {
  __shared__ float As[BM * LDA];
  __shared__ float Bs[NEMB * LDA];
  int t = threadIdx.x;
  int row0 = blockIdx.x * BM;
  int s = blockIdx.y;
  int tr = t >> 4, tc = t & 15;
  float acc[4][5] = {{0.f}};
  float ssq0 = 0.f, ssq1 = 0.f;

  int kbeg = s * KC, kend = kbeg + KC;
  for (int k0 = kbeg; k0 < kend; k0 += BK) {
    int r = t >> 3, dg = t & 7;
    {
      int gr = row0 + r;
      float4 v = make_float4(0.f, 0.f, 0.f, 0.f);
      if (gr < ROWS) v = *(const float4*)(feats + (size_t)gr * D + k0 + dg * 4);
      ssq0 += v.x * v.x + v.y * v.y + v.z * v.z + v.w * v.w;
      *(float4*)(As + r * LDA + dg * 4) = v;
    }
    {
      int gr = row0 + 32 + r;
      float4 v = make_float4(0.f, 0.f, 0.f, 0.f);
      if (gr < ROWS) v = *(const float4*)(feats + (size_t)gr * D + k0 + dg * 4);
      ssq1 += v.x * v.x + v.y * v.y + v.z * v.z + v.w * v.w;
      *(float4*)(As + (32 + r) * LDA + dg * 4) = v;
    }
    #pragma unroll
    for (int it = 0; it < 3; ++it) {
      int i = t + it * 256;
      if (i < NEMB * 8) {
        int rb = i >> 3, dgb = i & 7;
        float4 v = *(const float4*)(emb + (size_t)rb * D + k0 + dgb * 4);
        *(float4*)(Bs + rb * LDA + dgb * 4) = v;
      }
    }
    __syncthreads();
    #pragma unroll
    for (int dd = 0; dd < BK; dd += 4) {
      float4 a[4], b[5];
      #pragma unroll
      for (int j = 0; j < 4; ++j)  a[j]  = *(const float4*)(As + (tr * 4 + j) * LDA + dd);
      #pragma unroll
      for (int i2 = 0; i2 < 5; ++i2) b[i2] = *(const float4*)(Bs + (tc + i2 * 16) * LDA + dd);
      #pragma unroll
      for (int j = 0; j < 4; ++j)
        #pragma unroll
        for (int i2 = 0; i2 < 5; ++i2)
          acc[j][i2] += a[j].x * b[i2].x + a[j].y * b[i2].y +
                        a[j].z * b[i2].z + a[j].w * b[i2].w;
    }
    __syncthreads();
  }

  #pragma unroll
  for (int off = 4; off > 0; off >>= 1) {
    ssq0 += __shfl_down(ssq0, off, 8);
    ssq1 += __shfl_down(ssq1, off, 8);
  }
  if ((t & 7) == 0) {
    int r = t >> 3;
    int gr0 = row0 + r, gr1 = row0 + 32 + r;
    if (gr0 < ROWS) fpart[(size_t)s * ROWS + gr0] = ssq0;
    if (gr1 < ROWS) fpart[(size_t)s * ROWS + gr1] = ssq1;
  }

  float* pplane = part + (size_t)s * PLANE;
  #pragma unroll
  for (int j = 0; j < 4; ++j) {
    int gr = row0 + tr * 4 + j;
    if (gr >= ROWS) continue;
    int b_ = gr / K;
    int k  = gr - b_ * K;
    #pragma unroll
    for (int i2 = 0; i2 < 5; ++i2) {
      int n = tc + i2 * 16;
      pplane[((size_t)(b_ * NEMB + n)) * K + k] = acc[j][i2];
    }
  }
}

// -------- reduce partials -> cosim (all loads/stores coalesced) --------------
__global__ __launch_bounds__(256) void reduce_kernel(
    const float* __restrict__ part, const float* __restrict__ fpart,
    const float* __restrict__ e_norm, float* __restrict__ cosim) {
  size_t e = (size_t)blockIdx.x * 256 + threadIdx.x;
  if (e >= PLANE) return;
  int bn = (int)(e / K);
  int k  = (int)(e - (size_t)bn * K);
  int b_ = bn / NEMB;
  int n  = bn - b_ * NEMB;
  int gr = b_ * K + k;
  float dot = 0.f, fn2 = 0.f;
  #pragma unroll
  for (int s = 0; s < SPLIT; ++s) {
    dot += part[(size_t)s * PLANE + e];
    fn2 += fpart[(size_t)s * ROWS + gr];
  }
  cosim[e] = dot / (sqrtf(fn2) * e_norm[n] + EPS);
}

// ---------------- separable bicubic resize -----------------------------------
// grid: x = 43 chunks of 14 output rows, y = 320 images (b*80+n)
// No VMEM in hot loops: 14-entry weight table + clamped row offsets in LDS.
__global__ __launch_bounds__(256) void resize_kernel(
    const float* __restrict__ cosim, const float4* __restrict__ gtw,
    float* __restrict__ out) {
  __shared__ float img[5 * P];     // staged input rows
  __shared__ float tmp[5 * TGT];   // W-resized rows
  __shared__ float4 wq[14];
  __shared__ int4 ro[14];

  int bn = blockIdx.y;
  int c  = blockIdx.x;
  int t  = threadIdx.x;

  int hmin = max(0, c - 2), hmax = min(P - 1, c + 2);
  int NH = hmax - hmin + 1;

  if (t < 14) {
    wq[t] = gtw[t];
    int hb = c - 2 + (t >= 7);            // tap -1 row index for output row 14c+t
    int4 o;
    o.x = min(P - 1, max(0, hb))     - hmin;
    o.y = min(P - 1, max(0, hb + 1)) - hmin;
    o.z = min(P - 1, max(0, hb + 2)) - hmin;
    o.w = min(P - 1, max(0, hb + 3)) - hmin;
    ro[t] = o;
  }
  const float* src = cosim + (size_t)bn * (P * P) + hmin * P;
  for (int i = t; i < NH * P; i += 256) img[i] = src[i];
  __syncthreads();

  // phase 1: horizontal resize of the NH staged rows
  for (int i = t; i < NH * TGT; i += 256) {
    int h = i / TGT;
    int W = i - h * TGT;
    int m = W / 14;
    int j = W - m * 14;
    int wb = m - 2 + (j >= 7);            // tap -1 column index (exact)
    float4 w = wq[j];
    const float* rowp = img + h * P;
    int i0 = min(P - 1, max(0, wb));
    int i1 = min(P - 1, max(0, wb + 1));
    int i2 = min(P - 1, max(0, wb + 2));
    int i3 = min(P - 1, max(0, wb + 3));
    tmp[i] = w.x * rowp[i0] + w.y * rowp[i1] +
             w.z * rowp[i2] + w.w * rowp[i3];
  }
  __syncthreads();

  // phase 2: vertical resize, float2 stores
  int H0 = c * 14;
  float* obase = out + (size_t)bn * TGT * TGT;
  constexpr int PAIRS = TGT / 2; // 301
  for (int i = t; i < 14 * PAIRS; i += 256) {
    int r  = i / PAIRS;
    int pw = i - r * PAIRS;
    float4 hw = wq[r];
    int4 o = ro[r];
    const float* b0 = tmp + pw * 2;
    float2 a0 = *(const float2*)(b0 + o.x * TGT);
    float2 a1 = *(const float2*)(b0 + o.y * TGT);
    float2 a2 = *(const float2*)(b0 + o.z * TGT);
    float2 a3 = *(const float2*)(b0 + o.w * TGT);
    float2 ov;
    ov.x = hw.x * a0.x + hw.y * a1.x + hw.z * a2.x + hw.w * a3.x;
    ov.y = hw.x * a0.y + hw.y * a1.y + hw.z * a2.y + hw.w * a3.y;
    *(float2*)(obase + (size_t)(H0 + r) * TGT + pw * 2) = ov;
  }
}

// ---------------- launch ------------------------------------------------------
extern "C" void kernel_launch(void* const* d_in, const int* in_sizes, int n_in,
                              void* d_out, int out_size, void* d_ws, size_t ws_size,
                              hipStream_t stream) {
  const float* feats = (const float*)d_in[0];
  const float* emb   = (const float*)d_in[1];
  float* out = (float*)d_out;
  char* ws = (char*)d_ws;

  auto align64 = [](size_t x) { return (x + 63) & ~(size_t)63; };
  size_t off = 0;
  float* cosim  = (float*)(ws + off); off = align64(off + PLANE * 4);
  float* e_norm = (float*)(ws + off); off = align64(off + NEMB * 4);
  float4* gtw   = (float4*)(ws + off); off = align64(off + 14 * 16);

  // split-K partials live in d_out (scratch): consumed by reduce_kernel
  // BEFORE resize_kernel overwrites d_out. Same-stream ordering = race-free.
  float* part  = (float*)d_out;                      // SPLIT*PLANE floats (18.9 MB)
  float* fpart = part + (size_t)SPLIT * PLANE;       // SPLIT*ROWS floats (237 KB)

  prep_kernel<<<dim3(NEMB + 1), dim3(256), 0, stream>>>(emb, e_norm, gtw);
  gemm_partial<<<dim3((ROWS + BM - 1) / BM, SPLIT), dim3(256), 0, stream>>>(
      feats, emb, part, fpart);
  reduce_kernel<<<dim3((int)((PLANE + 255) / 256)), dim3(256), 0, stream>>>(
      part, fpart, e_norm, cosim);
  resize_kernel<<<dim3(43, 320), dim3(256), 0, stream>>>(cosim, gtw, out);
}

// Round 4
// 184.674 us; speedup vs baseline: 1.3467x; 1.0131x over previous
//
#include <hip/hip_runtime.h>
#include <math.h>

#define EPS 1e-8f
constexpr int D     = 1024;
constexpr int NEMB  = 80;
constexpr int K     = 1849;
constexpr int BATCH = 4;
constexpr int P     = 43;
constexpr int TGT   = 602;
constexpr int ROWS  = BATCH * K;                   // 7396
constexpr size_t PLANE = (size_t)BATCH * NEMB * K; // 591,680
constexpr int SPLIT = 8;
constexpr int KC    = D / SPLIT;                   // 128

// ---------------- bicubic tap weights (exact fp64, matches numpy) -----------
__device__ inline double cubic_w(double x) {
  const double A = -0.75;
  x = fabs(x);
  if (x <= 1.0) return ((A + 2.0) * x - (A + 3.0)) * x * x + 1.0;
  if (x < 2.0)  return A * (((x - 5.0) * x + 8.0) * x - 4.0);
  return 0.0;
}

__device__ inline float block_reduce_sum256(float v) {
  #pragma unroll
  for (int off = 32; off > 0; off >>= 1) v += __shfl_down(v, off, 64);
  __shared__ float red[4];
  int lane = threadIdx.x & 63, wid = threadIdx.x >> 6;
  if (lane == 0) red[wid] = v;
  __syncthreads();
  float r = 0.f;
  if (threadIdx.x == 0) r = red[0] + red[1] + red[2] + red[3];
  return r;
}

// blocks 0..79: e_norm rows; block 80: the 14-entry periodic weight table.
// scale = 43/602 = 1/14 exactly -> weights repeat with period 14 and
// base(i) = i/14 - 2 + (i%14 >= 7) exactly.
__global__ __launch_bounds__(256) void prep_kernel(
    const float* __restrict__ emb, float* __restrict__ e_norm,
    float4* __restrict__ gtw) {
  int bid = blockIdx.x;
  if (bid < NEMB) {
    float4 v = ((const float4*)(emb + (size_t)bid * D))[threadIdx.x];
    float s = v.x * v.x + v.y * v.y + v.z * v.z + v.w * v.w;
    s = block_reduce_sum256(s);
    if (threadIdx.x == 0) e_norm[bid] = sqrtf(s);
  } else {
    int j = threadIdx.x;
    if (j < 14) {
      double scale = (double)P / (double)TGT;
      double src = ((double)j + 0.5) * scale - 0.5;
      double fb = floor(src);
      double t = src - fb;
      float4 w;
      w.x = (float)cubic_w(t + 1.0);
      w.y = (float)cubic_w(t);
      w.z = (float)cubic_w(t - 1.0);
      w.w = (float)cubic_w(t - 2.0);
      gtw[j] = w;
    }
  }
}

// -------- split-K GEMM: partial dot [s][b][n][k] + partial sumsq [s][gr] ----
constexpr int BM  = 64;
constexpr int BK  = 32;
constexpr int LDA = 36; // padded LDS row stride (floats), 16B aligned

__global__ __launch_bounds__(256) void gemm_partial(
    const float* __restrict__ feats, const float* __restrict__ emb,
    float* __restrict__ part, float* __restrict__ fpart) {
  __shared__ float As[BM * LDA];
  __shared__ float Bs[NEMB * LDA];
  int t = threadIdx.x;
  int row0 = blockIdx.x * BM;
  int s = blockIdx.y;
  int tr = t >> 4, tc = t & 15;
  float acc[4][5] = {{0.f}};
  float ssq0 = 0.f, ssq1 = 0.f;

  int kbeg = s * KC, kend = kbeg + KC;
  for (int k0 = kbeg; k0 < kend; k0 += BK) {
    int r = t >> 3, dg = t & 7;
    {
      int gr = row0 + r;
      float4 v = make_float4(0.f, 0.f, 0.f, 0.f);
      if (gr < ROWS) v = *(const float4*)(feats + (size_t)gr * D + k0 + dg * 4);
      ssq0 += v.x * v.x + v.y * v.y + v.z * v.z + v.w * v.w;
      *(float4*)(As + r * LDA + dg * 4) = v;
    }
    {
      int gr = row0 + 32 + r;
      float4 v = make_float4(0.f, 0.f, 0.f, 0.f);
      if (gr < ROWS) v = *(const float4*)(feats + (size_t)gr * D + k0 + dg * 4);
      ssq1 += v.x * v.x + v.y * v.y + v.z * v.z + v.w * v.w;
      *(float4*)(As + (32 + r) * LDA + dg * 4) = v;
    }
    #pragma unroll
    for (int it = 0; it < 3; ++it) {
      int i = t + it * 256;
      if (i < NEMB * 8) {
        int rb = i >> 3, dgb = i & 7;
        float4 v = *(const float4*)(emb + (size_t)rb * D + k0 + dgb * 4);
        *(float4*)(Bs + rb * LDA + dgb * 4) = v;
      }
    }
    __syncthreads();
    #pragma unroll
    for (int dd = 0; dd < BK; dd += 4) {
      float4 a[4], b[5];
      #pragma unroll
      for (int j = 0; j < 4; ++j)  a[j]  = *(const float4*)(As + (tr * 4 + j) * LDA + dd);
      #pragma unroll
      for (int i2 = 0; i2 < 5; ++i2) b[i2] = *(const float4*)(Bs + (tc + i2 * 16) * LDA + dd);
      #pragma unroll
      for (int j = 0; j < 4; ++j)
        #pragma unroll
        for (int i2 = 0; i2 < 5; ++i2)
          acc[j][i2] += a[j].x * b[i2].x + a[j].y * b[i2].y +
                        a[j].z * b[i2].z + a[j].w * b[i2].w;
    }
    __syncthreads();
  }

  #pragma unroll
  for (int off = 4; off > 0; off >>= 1) {
    ssq0 += __shfl_down(ssq0, off, 8);
    ssq1 += __shfl_down(ssq1, off, 8);
  }
  if ((t & 7) == 0) {
    int r = t >> 3;
    int gr0 = row0 + r, gr1 = row0 + 32 + r;
    if (gr0 < ROWS) fpart[(size_t)s * ROWS + gr0] = ssq0;
    if (gr1 < ROWS) fpart[(size_t)s * ROWS + gr1] = ssq1;
  }

  float* pplane = part + (size_t)s * PLANE;
  #pragma unroll
  for (int j = 0; j < 4; ++j) {
    int gr = row0 + tr * 4 + j;
    if (gr >= ROWS) continue;
    int b_ = gr / K;
    int k  = gr - b_ * K;
    #pragma unroll
    for (int i2 = 0; i2 < 5; ++i2) {
      int n = tc + i2 * 16;
      pplane[((size_t)(b_ * NEMB + n)) * K + k] = acc[j][i2];
    }
  }
}

// -------- reduce partials -> cosim (all loads/stores coalesced) --------------
__global__ __launch_bounds__(256) void reduce_kernel(
    const float* __restrict__ part, const float* __restrict__ fpart,
    const float* __restrict__ e_norm, float* __restrict__ cosim) {
  size_t e = (size_t)blockIdx.x * 256 + threadIdx.x;
  if (e >= PLANE) return;
  int bn = (int)(e / K);
  int k  = (int)(e - (size_t)bn * K);
  int b_ = bn / NEMB;
  int n  = bn - b_ * NEMB;
  int gr = b_ * K + k;
  float dot = 0.f, fn2 = 0.f;
  #pragma unroll
  for (int s = 0; s < SPLIT; ++s) {
    dot += part[(size_t)s * PLANE + e];
    fn2 += fpart[(size_t)s * ROWS + gr];
  }
  cosim[e] = dot / (sqrtf(fn2) * e_norm[n] + EPS);
}

// ---------------- separable bicubic resize (register version) ----------------
// grid: x = 43 chunks of 14 output rows, y = 320 images. 320 threads.
// Each thread owns one float2 output column for all 14 rows: horizontal
// resize results held in registers (ta/tb[5]); vertical tap-row offsets are
// compile-time constants (6 static clamp patterns). No LDS tmp, 1 barrier.
__global__ __launch_bounds__(320) void resize_kernel(
    const float* __restrict__ cosim, const float4* __restrict__ gtw,
    float* __restrict__ out) {
  __shared__ float img[5 * P];   // 860 B: the <=5 needed input rows
  __shared__ float4 wq[14];

  int bn = blockIdx.y;
  int c  = blockIdx.x;
  int t  = threadIdx.x;

  int hmin = max(0, c - 2), hmax = min(P - 1, c + 2);
  int NH = hmax - hmin + 1;

  if (t < 14) wq[t] = gtw[t];
  const float* src = cosim + (size_t)bn * (P * P) + hmin * P;
  for (int i = t; i < NH * P; i += 320) img[i] = src[i];
  __syncthreads();

  int pw = t;
  if (pw >= TGT / 2) return;   // no barriers after this point

  int W0 = pw * 2;
  int m0 = W0 / 14;
  int j0 = W0 - m0 * 14;
  int wb0 = m0 - 2 + (j0 >= 7);
  int j1 = (j0 == 13) ? 0 : j0 + 1;
  int d  = (j0 == 6) ? 1 : 0;
  float4 w0 = wq[j0], w1 = wq[j1];

  int i0 = min(P - 1, max(0, wb0));
  int i1 = min(P - 1, max(0, wb0 + 1));
  int i2 = min(P - 1, max(0, wb0 + 2));
  int i3 = min(P - 1, max(0, wb0 + 3));
  int i4 = min(P - 1, max(0, wb0 + 4));

  float ta[5], tb[5];
  #pragma unroll
  for (int h = 0; h < 5; ++h) {
    const float* rowp = img + h * P;
    float v0 = rowp[i0], v1 = rowp[i1], v2 = rowp[i2], v3 = rowp[i3], v4 = rowp[i4];
    ta[h] = w0.x * v0 + w0.y * v1 + w0.z * v2 + w0.w * v3;
    float u0 = d ? v1 : v0;
    float u1 = d ? v2 : v1;
    float u2 = d ? v3 : v2;
    float u3 = d ? v4 : v3;
    tb[h] = w1.x * u0 + w1.y * u1 + w1.z * u2 + w1.w * u3;
  }

  float* op = out + (size_t)bn * TGT * TGT + (size_t)(c * 14) * TGT + W0;

  #define ROWS7(R0, a0, a1, a2, a3)                                        \
    _Pragma("unroll")                                                      \
    for (int r = R0; r < R0 + 7; ++r) {                                    \
      float4 hw = wq[r];                                                   \
      float ox = hw.x * ta[a0] + hw.y * ta[a1] + hw.z * ta[a2] + hw.w * ta[a3]; \
      float oy = hw.x * tb[a0] + hw.y * tb[a1] + hw.z * tb[a2] + hw.w * tb[a3]; \
      *(float2*)(op + (size_t)r * TGT) = make_float2(ox, oy);              \
    }

  if (c >= 2 && c <= 40) {        // interior: no clamping
    ROWS7(0, 0, 1, 2, 3)
    ROWS7(7, 1, 2, 3, 4)
  } else if (c == 0) {            // hmin=0, NH=3
    ROWS7(0, 0, 0, 0, 1)
    ROWS7(7, 0, 0, 1, 2)
  } else if (c == 1) {            // hmin=0, NH=4
    ROWS7(0, 0, 0, 1, 2)
    ROWS7(7, 0, 1, 2, 3)
  } else if (c == 41) {           // hmin=39, NH=4
    ROWS7(0, 0, 1, 2, 3)
    ROWS7(7, 1, 2, 3, 3)
  } else {                        // c == 42: hmin=40, NH=3
    ROWS7(0, 0, 1, 2, 2)
    ROWS7(7, 1, 2, 2, 2)
  }
  #undef ROWS7
}

// ---------------- launch ------------------------------------------------------
extern "C" void kernel_launch(void* const* d_in, const int* in_sizes, int n_in,
                              void* d_out, int out_size, void* d_ws, size_t ws_size,
                              hipStream_t stream) {
  const float* feats = (const float*)d_in[0];
  const float* emb   = (const float*)d_in[1];
  float* out = (float*)d_out;
  char* ws = (char*)d_ws;

  auto align64 = [](size_t x) { return (x + 63) & ~(size_t)63; };
  size_t off = 0;
  float* cosim  = (float*)(ws + off); off = align64(off + PLANE * 4);
  float* e_norm = (float*)(ws + off); off = align64(off + NEMB * 4);
  float4* gtw   = (float4*)(ws + off); off = align64(off + 14 * 16);

  // split-K partials live in d_out (scratch): consumed by reduce_kernel
  // BEFORE resize_kernel overwrites d_out. Same-stream ordering = race-free.
  float* part  = (float*)d_out;                      // SPLIT*PLANE floats (18.9 MB)
  float* fpart = part + (size_t)SPLIT * PLANE;       // SPLIT*ROWS floats (237 KB)

  prep_kernel<<<dim3(NEMB + 1), dim3(256), 0, stream>>>(emb, e_norm, gtw);
  gemm_partial<<<dim3((ROWS + BM - 1) / BM, SPLIT), dim3(256), 0, stream>>>(
      feats, emb, part, fpart);
  reduce_kernel<<<dim3((int)((PLANE + 255) / 256)), dim3(256), 0, stream>>>(
      part, fpart, e_norm, cosim);
  resize_kernel<<<dim3(43, 320), dim3(320), 0, stream>>>(cosim, gtw, out);
}

// Round 6
// 175.626 us; speedup vs baseline: 1.4161x; 1.0515x over previous
//
#include <hip/hip_runtime.h>
#include <math.h>

#define EPS 1e-8f
constexpr int D     = 1024;
constexpr int NEMB  = 80;
constexpr int K     = 1849;
constexpr int BATCH = 4;
constexpr int P     = 43;
constexpr int TGT   = 602;
constexpr int ROWS  = BATCH * K;                   // 7396
constexpr size_t PLANE = (size_t)BATCH * NEMB * K; // 591,680
constexpr int SPLIT = 8;
constexpr int KC    = D / SPLIT;                   // 128

typedef float nfloat4 __attribute__((ext_vector_type(4))); // native vec for nontemporal builtins

// ---------------- bicubic tap weights (exact fp64, matches numpy) -----------
__device__ inline double cubic_w(double x) {
  const double A = -0.75;
  x = fabs(x);
  if (x <= 1.0) return ((A + 2.0) * x - (A + 3.0)) * x * x + 1.0;
  if (x < 2.0)  return A * (((x - 5.0) * x + 8.0) * x - 4.0);
  return 0.0;
}

__device__ inline float block_reduce_sum256(float v) {
  #pragma unroll
  for (int off = 32; off > 0; off >>= 1) v += __shfl_down(v, off, 64);
  __shared__ float red[4];
  int lane = threadIdx.x & 63, wid = threadIdx.x >> 6;
  if (lane == 0) red[wid] = v;
  __syncthreads();
  float r = 0.f;
  if (threadIdx.x == 0) r = red[0] + red[1] + red[2] + red[3];
  return r;
}

// blocks 0..79: e_norm rows; block 80: the 14-entry periodic weight table.
__global__ __launch_bounds__(256) void prep_kernel(
    const float* __restrict__ emb, float* __restrict__ e_norm,
    float4* __restrict__ gtw) {
  int bid = blockIdx.x;
  if (bid < NEMB) {
    float4 v = ((const float4*)(emb + (size_t)bid * D))[threadIdx.x];
    float s = v.x * v.x + v.y * v.y + v.z * v.z + v.w * v.w;
    s = block_reduce_sum256(s);
    if (threadIdx.x == 0) e_norm[bid] = sqrtf(s);
  } else {
    int j = threadIdx.x;
    if (j < 14) {
      double scale = (double)P / (double)TGT;
      double src = ((double)j + 0.5) * scale - 0.5;
      double fb = floor(src);
      double t = src - fb;
      float4 w;
      w.x = (float)cubic_w(t + 1.0);
      w.y = (float)cubic_w(t);
      w.z = (float)cubic_w(t - 1.0);
      w.w = (float)cubic_w(t - 2.0);
      gtw[j] = w;
    }
  }
}

// -------- split-K GEMM, 2-phase pipelined (prefetch tile t+1 during compute)
constexpr int BM  = 64;
constexpr int BK  = 32;
constexpr int LDA = 36; // padded LDS row stride (floats), 16B aligned
constexpr int NT  = KC / BK; // 4 K-tiles per block

__device__ inline float dot4(float4 v) {
  return v.x * v.x + v.y * v.y + v.z * v.z + v.w * v.w;
}

__global__ __launch_bounds__(256) void gemm_partial(
    const float* __restrict__ feats, const float* __restrict__ emb,
    float* __restrict__ part, float* __restrict__ fpart) {
  __shared__ float As[BM * LDA];
  __shared__ float Bs[NEMB * LDA];
  int t = threadIdx.x;
  int row0 = blockIdx.x * BM;
  int s = blockIdx.y;
  int tr = t >> 4, tc = t & 15;
  float acc[4][5] = {{0.f}};
  float ssq0 = 0.f, ssq1 = 0.f;

  int r = t >> 3, dg = t & 7;         // staging: 8 threads/row, 4 floats each
  int gr0 = row0 + r, gr1 = row0 + 32 + r;
  bool ok0 = gr0 < ROWS, ok1 = gr1 < ROWS;
  const float* pA0 = feats + (size_t)gr0 * D + dg * 4;
  const float* pA1 = feats + (size_t)gr1 * D + dg * 4;
  const float* pB0 = emb + (size_t)r * D + dg * 4;          // rows 0..31
  const float* pB1 = emb + (size_t)(32 + r) * D + dg * 4;   // rows 32..63
  const float* pB2 = emb + (size_t)(64 + r) * D + dg * 4;   // rows 64..79 (t<128)
  bool okB2 = t < 128;

  int kbeg = s * KC;
  const float4 zero = make_float4(0.f, 0.f, 0.f, 0.f);
  float4 a0 = ok0 ? *(const float4*)(pA0 + kbeg) : zero;
  float4 a1 = ok1 ? *(const float4*)(pA1 + kbeg) : zero;
  float4 b0 = *(const float4*)(pB0 + kbeg);
  float4 b1 = *(const float4*)(pB1 + kbeg);
  float4 b2 = okB2 ? *(const float4*)(pB2 + kbeg) : zero;

  for (int tile = 0; tile < NT; ++tile) {
    // phase A: commit prefetched regs to LDS (+ssq)
    ssq0 += dot4(a0);
    *(float4*)(As + r * LDA + dg * 4) = a0;
    ssq1 += dot4(a1);
    *(float4*)(As + (32 + r) * LDA + dg * 4) = a1;
    *(float4*)(Bs + r * LDA + dg * 4) = b0;
    *(float4*)(Bs + (32 + r) * LDA + dg * 4) = b1;
    if (okB2) *(float4*)(Bs + (64 + r) * LDA + dg * 4) = b2;
    __syncthreads();

    // phase B: issue next tile's loads (latency hides under the dd loop)
    if (tile + 1 < NT) {
      int k1 = kbeg + (tile + 1) * BK;
      a0 = ok0 ? *(const float4*)(pA0 + k1) : zero;
      a1 = ok1 ? *(const float4*)(pA1 + k1) : zero;
      b0 = *(const float4*)(pB0 + k1);
      b1 = *(const float4*)(pB1 + k1);
      if (okB2) b2 = *(const float4*)(pB2 + k1);
    }

    #pragma unroll
    for (int dd = 0; dd < BK; dd += 4) {
      float4 a[4], b[5];
      #pragma unroll
      for (int j = 0; j < 4; ++j)  a[j]  = *(const float4*)(As + (tr * 4 + j) * LDA + dd);
      #pragma unroll
      for (int i2 = 0; i2 < 5; ++i2) b[i2] = *(const float4*)(Bs + (tc + i2 * 16) * LDA + dd);
      #pragma unroll
      for (int j = 0; j < 4; ++j)
        #pragma unroll
        for (int i2 = 0; i2 < 5; ++i2)
          acc[j][i2] += a[j].x * b[i2].x + a[j].y * b[i2].y +
                        a[j].z * b[i2].z + a[j].w * b[i2].w;
    }
    __syncthreads();
  }

  #pragma unroll
  for (int off = 4; off > 0; off >>= 1) {
    ssq0 += __shfl_down(ssq0, off, 8);
    ssq1 += __shfl_down(ssq1, off, 8);
  }
  if ((t & 7) == 0) {
    if (gr0 < ROWS) fpart[(size_t)s * ROWS + gr0] = ssq0;
    if (gr1 < ROWS) fpart[(size_t)s * ROWS + gr1] = ssq1;
  }

  float* pplane = part + (size_t)s * PLANE;
  #pragma unroll
  for (int j = 0; j < 4; ++j) {
    int gr = row0 + tr * 4 + j;
    if (gr >= ROWS) continue;
    int b_ = gr / K;
    int k  = gr - b_ * K;
    #pragma unroll
    for (int i2 = 0; i2 < 5; ++i2) {
      int n = tc + i2 * 16;
      pplane[((size_t)(b_ * NEMB + n)) * K + k] = acc[j][i2];
    }
  }
}

// -------- reduce partials -> cosim (all loads/stores coalesced) --------------
__global__ __launch_bounds__(256) void reduce_kernel(
    const float* __restrict__ part, const float* __restrict__ fpart,
    const float* __restrict__ e_norm, float* __restrict__ cosim) {
  size_t e = (size_t)blockIdx.x * 256 + threadIdx.x;
  if (e >= PLANE) return;
  int bn = (int)(e / K);
  int k  = (int)(e - (size_t)bn * K);
  int b_ = bn / NEMB;
  int n  = bn - b_ * NEMB;
  int gr = b_ * K + k;
  float dot = 0.f, fn2 = 0.f;
  #pragma unroll
  for (int s = 0; s < SPLIT; ++s) {
    dot += part[(size_t)s * PLANE + e];
    fn2 += fpart[(size_t)s * ROWS + gr];
  }
  cosim[e] = dot / (sqrtf(fn2) * e_norm[n] + EPS);
}

// ---------------- separable bicubic resize -----------------------------------
// grid (43, 320), 320 threads. Register-based compute (R4), results staged in
// LDS; the block's 33,712 contiguous bytes stream out as 2107 aligned
// nontemporal 16B stores (no L2 allocate), matching the fill's write path.
__global__ __launch_bounds__(320) void resize_kernel(
    const float* __restrict__ cosim, const float4* __restrict__ gtw,
    float* __restrict__ out) {
  __shared__ float img[5 * P];        // 860 B
  __shared__ float4 wq[14];
  __shared__ float obuf[14 * TGT];    // 33,712 B packed, == out block range

  int bn = blockIdx.y;
  int c  = blockIdx.x;
  int t  = threadIdx.x;

  int hmin = max(0, c - 2), hmax = min(P - 1, c + 2);
  int NH = hmax - hmin + 1;

  if (t < 14) wq[t] = gtw[t];
  const float* src = cosim + (size_t)bn * (P * P) + hmin * P;
  for (int i = t; i < NH * P; i += 320) img[i] = src[i];
  __syncthreads();

  int pw = t;
  if (pw < TGT / 2) {
    int W0 = pw * 2;
    int m0 = W0 / 14;
    int j0 = W0 - m0 * 14;
    int wb0 = m0 - 2 + (j0 >= 7);
    int j1 = (j0 == 13) ? 0 : j0 + 1;
    int d  = (j0 == 6) ? 1 : 0;
    float4 w0 = wq[j0], w1 = wq[j1];

    int i0 = min(P - 1, max(0, wb0));
    int i1 = min(P - 1, max(0, wb0 + 1));
    int i2 = min(P - 1, max(0, wb0 + 2));
    int i3 = min(P - 1, max(0, wb0 + 3));
    int i4 = min(P - 1, max(0, wb0 + 4));

    float ta[5], tb[5];
    #pragma unroll
    for (int h = 0; h < 5; ++h) {
      const float* rowp = img + h * P;
      float v0 = rowp[i0], v1 = rowp[i1], v2 = rowp[i2], v3 = rowp[i3], v4 = rowp[i4];
      ta[h] = w0.x * v0 + w0.y * v1 + w0.z * v2 + w0.w * v3;
      float u0 = d ? v1 : v0;
      float u1 = d ? v2 : v1;
      float u2 = d ? v3 : v2;
      float u3 = d ? v4 : v3;
      tb[h] = w1.x * u0 + w1.y * u1 + w1.z * u2 + w1.w * u3;
    }

    #define ROWS7(R0, a0, a1, a2, a3)                                        \
      _Pragma("unroll")                                                      \
      for (int r = R0; r < R0 + 7; ++r) {                                    \
        float4 hw = wq[r];                                                   \
        float ox = hw.x * ta[a0] + hw.y * ta[a1] + hw.z * ta[a2] + hw.w * ta[a3]; \
        float oy = hw.x * tb[a0] + hw.y * tb[a1] + hw.z * tb[a2] + hw.w * tb[a3]; \
        *(float2*)(obuf + r * TGT + W0) = make_float2(ox, oy);               \
      }

    if (c >= 2 && c <= 40) {
      ROWS7(0, 0, 1, 2, 3)
      ROWS7(7, 1, 2, 3, 4)
    } else if (c == 0) {
      ROWS7(0, 0, 0, 0, 1)
      ROWS7(7, 0, 0, 1, 2)
    } else if (c == 1) {
      ROWS7(0, 0, 0, 1, 2)
      ROWS7(7, 0, 1, 2, 3)
    } else if (c == 41) {
      ROWS7(0, 0, 1, 2, 3)
      ROWS7(7, 1, 2, 3, 3)
    } else {
      ROWS7(0, 0, 1, 2, 2)
      ROWS7(7, 1, 2, 2, 2)
    }
    #undef ROWS7
  }
  __syncthreads();

  // store phase: 14*602 floats = 2107 16B vectors, all 16B-aligned
  // (33712 = 2107*16; image stride 1,449,616 and chunk stride 33,712 are x16)
  nfloat4* dst = (nfloat4*)(out + (size_t)bn * TGT * TGT + (size_t)c * 14 * TGT);
  const nfloat4* sb = (const nfloat4*)obuf;
  constexpr int NVEC = 14 * TGT / 4; // 2107
  for (int i = t; i < NVEC; i += 320) {
    __builtin_nontemporal_store(sb[i], dst + i);
  }
}

// ---------------- launch ------------------------------------------------------
extern "C" void kernel_launch(void* const* d_in, const int* in_sizes, int n_in,
                              void* d_out, int out_size, void* d_ws, size_t ws_size,
                              hipStream_t stream) {
  const float* feats = (const float*)d_in[0];
  const float* emb   = (const float*)d_in[1];
  float* out = (float*)d_out;
  char* ws = (char*)d_ws;

  auto align64 = [](size_t x) { return (x + 63) & ~(size_t)63; };
  size_t off = 0;
  float* cosim  = (float*)(ws + off); off = align64(off + PLANE * 4);
  float* e_norm = (float*)(ws + off); off = align64(off + NEMB * 4);
  float4* gtw   = (float4*)(ws + off); off = align64(off + 14 * 16);

  float* fpart = (float*)(ws + off); off = align64(off + (size_t)SPLIT * ROWS * 4);
  float* part  = (float*)(ws + off); off = align64(off + (size_t)SPLIT * PLANE * 4);

  prep_kernel<<<dim3(NEMB + 1), dim3(256), 0, stream>>>(emb, e_norm, gtw);
  gemm_partial<<<dim3((ROWS + BM - 1) / BM, SPLIT), dim3(256), 0, stream>>>(
      feats, emb, part, fpart);
  reduce_kernel<<<dim3((int)((PLANE + 255) / 256)), dim3(256), 0, stream>>>(
      part, fpart, e_norm, cosim);
  resize_kernel<<<dim3(43, 320), dim3(320), 0, stream>>>(cosim, gtw, out);
}